// Round 2
// baseline (25610.004 us; speedup 1.0000x reference)
//
#include <hip/hip_runtime.h>
#include <stdint.h>

// Encoder: 2-layer bidirectional masked LSTM. B=32 T=1024 D=H=512 G=4H=2048.
// v2: fused design — no separate GEMM, no global_load_lds, 48 MiB workspace.
//   memset cnt -> cvt x->xh(f16,time-major) -> cvt Wk,Wr -> REC(l0, h->d_out
//   scratch) -> sum_h(res1h=xh) -> memset d_out -> REC(l1, out+residual)
// REC: 64 persistent WGs (32/dir), per-direction lockstep via agent-scope
// counters in MALL; h exchanged through a 4-slot ring with 8B agent atomic
// loads (bypass stale per-XCD L2). x@Wk computed on the fly each step
// (overlaps the wait); h@Wr with Wr fragments resident in VGPRs.

#define B_ 32
#define T_ 1024
#define H_ 512
#define G_ 2048

typedef _Float16 f16;
typedef _Float16 f16x8 __attribute__((ext_vector_type(8)));
typedef float f32x4 __attribute__((ext_vector_type(4)));

#define AL(p) __hip_atomic_load((p), __ATOMIC_RELAXED, __HIP_MEMORY_SCOPE_AGENT)
#define AS(p, v) __hip_atomic_store((p), (v), __ATOMIC_RELAXED, __HIP_MEMORY_SCOPE_AGENT)
#define AADD(p, v) __hip_atomic_fetch_add((p), (v), __ATOMIC_RELAXED, __HIP_MEMORY_SCOPE_AGENT)

__device__ __forceinline__ float sigm(float x) { return 1.f / (1.f + __expf(-x)); }
__device__ __forceinline__ float tanh_(float x) { return 1.f - 2.f / (__expf(2.f * x) + 1.f); }

// ---------------------------------------------------------------- converts
// x [b][t][512] f32 -> xh [t][b][512] f16 (time-major slices for the rec)
__global__ void cvt_x_t(const float* __restrict__ x, f16* __restrict__ xh) {
  size_t i = ((size_t)blockIdx.x * 256 + threadIdx.x) * 8;
  int t = (int)(i >> 14);
  int b = (int)((i >> 9) & 31);
  int k = (int)(i & 511);
  const float4* p = (const float4*)(x + (((size_t)b << 10) + (size_t)t) * 512 + k);
  float4 a = p[0], c = p[1];
  union { f16 h[8]; uint4 u; } r;
  r.h[0] = (f16)a.x; r.h[1] = (f16)a.y; r.h[2] = (f16)a.z; r.h[3] = (f16)a.w;
  r.h[4] = (f16)c.x; r.h[5] = (f16)c.y; r.h[6] = (f16)c.z; r.h[7] = (f16)c.w;
  *(uint4*)(xh + i) = r.u;
}

// W [z][512][2048] f32 -> Wb [z][2048][512] f16 (transposed: col-major frags)
__global__ void cvt_w(const float* __restrict__ W, f16* __restrict__ Wb) {
  __shared__ float tl[64][65];
  const float* src = W + (size_t)blockIdx.z * H_ * G_;
  f16* dst = Wb + (size_t)blockIdx.z * G_ * H_;
  int g0 = blockIdx.x * 64, k0 = blockIdx.y * 64;
  for (int i = threadIdx.x; i < 4096; i += 256) {
    int kk = i >> 6, gg = i & 63;
    tl[kk][gg] = src[(size_t)(k0 + kk) * G_ + g0 + gg];
  }
  __syncthreads();
  for (int i = threadIdx.x; i < 4096; i += 256) {
    int gg = i >> 6, kk = i & 63;
    dst[(size_t)(g0 + gg) * H_ + k0 + kk] = (f16)tl[kk][gg];
  }
}

// res1h = hf + hb (all time-major [t][b][512] f16)
__global__ void sum_h(const f16* __restrict__ a, const f16* __restrict__ b,
                      f16* __restrict__ r) {
  size_t i = ((size_t)blockIdx.x * 256 + threadIdx.x) * 8;
  f16x8 va = *(const f16x8*)(a + i), vb = *(const f16x8*)(b + i);
  *(f16x8*)(r + i) = va + vb;
}

// ---------------------------------------------------------------- recurrence
// 64 WGs x 512 thr. WG: dir=blk>>5, wgi=blk&31 owns h-cols [wgi*16,+16).
// 8 waves: mtile=wave&1 (16 batch rows), gate=wave>>1. Per wave per step:
// 16 MFMA x@Wk (overlaps wait) + 16 MFMA h@Wr (Wr frags resident in VGPRs).
__global__ __launch_bounds__(512, 2) void lstm_rec2(
    const f16* __restrict__ xh,    // [1024][32][512] layer input, time-major
    const f16* __restrict__ wkb,   // [2][2048][512] this layer's Wk^T f16
    const f16* __restrict__ wrb,   // [2][2048][512] this layer's Wr^T f16
    const float* __restrict__ biasL,  // [2][2048] this layer
    const void* __restrict__ maskp,
    f16* __restrict__ ring,        // [2][4][32][512]
    unsigned* __restrict__ cnt,    // [1024][8], pre-zeroed
    f16* __restrict__ hf,          // layer0: fwd h out [t][b][512] (d_out lo)
    f16* __restrict__ hb,          // layer0: bwd h out (d_out hi)
    float* __restrict__ out,       // layer1: final output [b][t][512]
    const f16* __restrict__ res1h, // layer1: residual, time-major
    const int layer) {
  const int wg = blockIdx.x;
  const int dir = wg >> 5, wgi = wg & 31;
  const int grp = dir * 4 + (wgi & 3);
  const int tid = threadIdx.x, wave = tid >> 6, lane = tid & 63;
  const int mtile = wave & 1, gate = wave >> 1;
  const int j0 = wgi * 16;

  __shared__ float zbuf[32][65];

  const int arow = mtile * 16 + (lane & 15);   // batch row (MFMA A lane)
  const int koff = (lane >> 4) << 3;           // k-offset within 32-chunk
  const int gcol = gate * H_ + j0 + (lane & 15);  // gate column (MFMA B lane)

  const f16* wr_d = wrb + (size_t)dir * G_ * H_ + (size_t)gcol * H_;
  const f16* wk_d = wkb + (size_t)dir * G_ * H_ + (size_t)gcol * H_;
  f16x8 wf[16];
#pragma unroll
  for (int kt = 0; kt < 16; ++kt) wf[kt] = *(const f16x8*)(wr_d + kt * 32 + koff);

  // gate-phase identity: thread = (batch cb, col cj)
  const int cb = tid >> 4, cj = tid & 15;
  const float* bb = biasL + (size_t)dir * G_;
  float bias4[4];
#pragma unroll
  for (int g = 0; g < 4; ++g) bias4[g] = bb[g * H_ + j0 + cj];

  const unsigned char* mbytes = (const unsigned char*)maskp;
  const unsigned* mwords = (const unsigned*)maskp;
  const bool bytelay = (mbytes[1] != 0);  // bool(1B) vs int32(4B) layout probe

  float hstate = 0.f, cstate = 0.f;
  f16* ringd = ring + (size_t)dir * 4 * B_ * H_;
  unsigned long long* cb64 = (unsigned long long*)cnt;
  const f32x4 vzero = {0.f, 0.f, 0.f, 0.f};

  for (int s = 0; s < T_; ++s) {
    const int t = dir ? (T_ - 1 - s) : s;
    // ---- x-part: acc = x[t] @ Wk tile (no cross-WG dependency)
    const f16* xp = xh + ((size_t)t * B_ + arow) * H_ + koff;
    f32x4 acc = vzero;
#pragma unroll
    for (int kt = 0; kt < 16; ++kt) {
      f16x8 xf = *(const f16x8*)(xp + kt * 32);
      f16x8 wk = *(const f16x8*)(wk_d + kt * 32 + koff);
      acc = __builtin_amdgcn_mfma_f32_16x16x32_f16(xf, wk, acc, 0, 0, 0);
    }
    // gate-phase prefetches (no cross-WG dependency)
    const size_t btm = (size_t)cb * T_ + t;
    const bool mv = bytelay ? (mbytes[btm] != 0) : (mwords[btm] != 0);
    float xr = 0.f;
    if (layer == 1 && dir == 0)
      xr = (float)res1h[((size_t)t * B_ + cb) * H_ + j0 + cj];

    // ---- h-part: wait for h[s-1], then acc += h[s-1] @ Wr tile
    if (s > 0) {
      unsigned long long* cp = cb64 + (size_t)(s - 1) * 4 + dir * 2;
      while (true) {
        unsigned long long a = AL(cp);
        unsigned long long b2 = AL(cp + 1);
        unsigned tot = (unsigned)(a & 0xffffffffu) + (unsigned)(a >> 32) +
                       (unsigned)(b2 & 0xffffffffu) + (unsigned)(b2 >> 32);
        if (tot == 32u) break;
        __builtin_amdgcn_s_sleep(1);
      }
      const f16* hp = ringd + (size_t)((s - 1) & 3) * B_ * H_ +
                      (size_t)arow * H_ + koff;
#pragma unroll
      for (int kt = 0; kt < 16; ++kt) {
        unsigned long long a0 = AL((const unsigned long long*)(hp + kt * 32));
        unsigned long long a1 = AL((const unsigned long long*)(hp + kt * 32 + 4));
        union { unsigned long long u[2]; f16x8 v; } cvt;
        cvt.u[0] = a0; cvt.u[1] = a1;
        acc = __builtin_amdgcn_mfma_f32_16x16x32_f16(cvt.v, wf[kt], acc, 0, 0, 0);
      }
    }
    // ---- spill z tile: row=(lane>>4)*4+r (batch), col=lane&15 (gate col)
    {
      int zr = mtile * 16 + ((lane >> 4) << 2), zc = gate * 16 + (lane & 15);
#pragma unroll
      for (int r = 0; r < 4; ++r) zbuf[zr + r][zc] = acc[r];
    }
    __syncthreads();

    // ---- gates (fp32 state)
    float zi = zbuf[cb][cj]      + bias4[0];
    float zf = zbuf[cb][16 + cj] + bias4[1];
    float zg = zbuf[cb][32 + cj] + bias4[2];
    float zo = zbuf[cb][48 + cj] + bias4[3];
    float ig = sigm(zi), fg = sigm(zf), gg = tanh_(zg), og = sigm(zo);
    float cn = fg * cstate + ig * gg;
    float hn = og * tanh_(cn);
    if (mv) { cstate = cn; hstate = hn; }  // masked steps carry h,c

    // ---- publish h to ring slot s&3 (agent scope -> MALL)
    f16 h16 = (f16)hstate;
    unsigned short hu = __builtin_bit_cast(unsigned short, h16);
    unsigned ob = (unsigned)__shfl_xor((int)hu, 1);
    unsigned pk = (unsigned)hu | ((ob & 0xffffu) << 16);
    if ((cj & 1) == 0) {
      unsigned* rdst = (unsigned*)(ringd + (size_t)(s & 3) * B_ * H_ +
                                   (size_t)cb * H_ + j0 + cj);
      AS(rdst, pk);
    }
    // ---- layer outputs
    if (layer == 0) {
      if ((cj & 1) == 0) {
        f16* hx = dir ? hb : hf;
        *(unsigned*)(hx + ((size_t)t * B_ + cb) * H_ + j0 + cj) = pk;
      }
    } else {
      atomicAdd(&out[btm * H_ + j0 + cj], hstate + xr);
    }
    // ---- release: drain stores, then signal step completion
    asm volatile("s_waitcnt vmcnt(0)" ::: "memory");
    __syncthreads();
    if (tid == 0) AADD(&cnt[s * 8 + grp], 1u);
  }
}

// ---------------------------------------------------------------- launch
extern "C" void kernel_launch(void* const* d_in, const int* in_sizes, int n_in,
                              void* d_out, int out_size, void* d_ws, size_t ws_size,
                              hipStream_t stream) {
  const float* x = (const float*)d_in[0];
  const void* maskp = (const void*)d_in[1];
  const float* Wk = (const float*)d_in[2];
  const float* Wr = (const float*)d_in[3];
  const float* bias = (const float*)d_in[4];
  float* out = (float*)d_out;
  (void)in_sizes; (void)n_in;

  // workspace carve (total 50,659,328 B = 48.3 MiB)
  char* ws = (char*)d_ws;
  f16* xh = (f16*)(ws);                            // 33,554,432  [1024][32][512] (reused as res1h)
  f16* wkb = (f16*)(ws + 33554432ull);             //  8,388,608  [2][2][2048][512]
  f16* wrb = (f16*)(ws + 41943040ull);             //  8,388,608  [2][2][2048][512]
  f16* ring = (f16*)(ws + 50331648ull);            //    262,144  [2][4][32][512]
  unsigned* cnt0 = (unsigned*)(ws + 50593792ull);  //     32,768  [1024][8]
  unsigned* cnt1 = (unsigned*)(ws + 50626560ull);  //     32,768
  if (ws_size < 50659328ull) return;  // fail loudly (wrong output), don't fault

  // d_out (64 MiB) doubles as layer-0 h scratch
  f16* hf = (f16*)d_out;                 // [1024][32][512] fwd h
  f16* hb = (f16*)d_out + 16777216ull;   // [1024][32][512] bwd h

  hipMemsetAsync(cnt0, 0, 65536, stream);  // covers cnt0+cnt1
  cvt_x_t<<<8192, 256, 0, stream>>>(x, xh);
  cvt_w<<<dim3(32, 8, 4), 256, 0, stream>>>(Wk, wkb);
  cvt_w<<<dim3(32, 8, 4), 256, 0, stream>>>(Wr, wrb);

  // layer 0: h streams into d_out scratch
  lstm_rec2<<<64, 512, 0, stream>>>(xh, wkb, wrb, bias, maskp, ring, cnt0,
                                    hf, hb, (float*)nullptr, (const f16*)nullptr, 0);
  sum_h<<<8192, 256, 0, stream>>>(hf, hb, xh);  // res1h overwrites xh

  // layer 1: final output (residual folded in by dir-0 WGs)
  hipMemsetAsync(d_out, 0, 67108864ull, stream);
  lstm_rec2<<<64, 512, 0, stream>>>(xh, wkb + 2ull * G_ * H_, wrb + 2ull * G_ * H_,
                                    bias + 2ull * G_, maskp, ring, cnt1,
                                    (f16*)nullptr, (f16*)nullptr, out, xh, 1);
}

// Round 3
// 18371.848 us; speedup vs baseline: 1.3940x; 1.3940x over previous
//
#include <hip/hip_runtime.h>
#include <stdint.h>

// Encoder: 2-layer bidirectional masked LSTM. B=32 T=1024 D=H=512 G=4H=2048.
// v3: XCD-local recurrence. 512 WGs launched; each reads HW_REG_XCC_ID and
// claims a role via agent atomics: first two XCDs to fill 32 WGs take one
// direction each (pigeonhole over 512 WGs guarantees >=2 XCDs fill; extras
// exit). Within a direction all 32 WGs share one XCD L2 -> h exchanged via
// plain stores/loads (write-through L2, first-touch addresses). Step flags
// stay in MALL (agent atomics) but only wave 0 of each WG polls.
// Layer-0 h ring = d_out scratch. Layer-1 ring in ws if it fits (host branch),
// else 8-slot MALL ring (v2-style, proven).

#define B_ 32
#define T_ 1024
#define H_ 512
#define G_ 2048

typedef _Float16 f16;
typedef _Float16 f16x8 __attribute__((ext_vector_type(8)));
typedef float f32x4 __attribute__((ext_vector_type(4)));

#define AL_U(p) __hip_atomic_load((p), __ATOMIC_RELAXED, __HIP_MEMORY_SCOPE_AGENT)
#define AS_U(p, v) __hip_atomic_store((p), (v), __ATOMIC_RELAXED, __HIP_MEMORY_SCOPE_AGENT)
#define AADD_U(p, v) __hip_atomic_fetch_add((p), (v), __ATOMIC_RELAXED, __HIP_MEMORY_SCOPE_AGENT)

struct Claim {
  unsigned cnt[8];     // per-XCD claim counters
  unsigned dirclaim;   // number of directions claimed
  int xcddir[8];       // 0=undecided, 1/2=dir+1, -1=unused XCD
  unsigned pad[15];
};

__device__ __forceinline__ float sigm(float x) { return 1.f / (1.f + __expf(-x)); }
__device__ __forceinline__ float tanh_(float x) { return 1.f - 2.f / (__expf(2.f * x) + 1.f); }

// ---------------------------------------------------------------- converts
// x [b][t][512] f32 -> xh [t][b][512] f16 (time-major)
__global__ void cvt_x_t(const float* __restrict__ x, f16* __restrict__ xh) {
  size_t i = ((size_t)blockIdx.x * 256 + threadIdx.x) * 8;
  int t = (int)(i >> 14);
  int b = (int)((i >> 9) & 31);
  int k = (int)(i & 511);
  const float4* p = (const float4*)(x + (((size_t)b << 10) + (size_t)t) * 512 + k);
  float4 a = p[0], c = p[1];
  union { f16 h[8]; uint4 u; } r;
  r.h[0] = (f16)a.x; r.h[1] = (f16)a.y; r.h[2] = (f16)a.z; r.h[3] = (f16)a.w;
  r.h[4] = (f16)c.x; r.h[5] = (f16)c.y; r.h[6] = (f16)c.z; r.h[7] = (f16)c.w;
  *(uint4*)(xh + i) = r.u;
}

// res1h = hf + hb (all time-major [t][b][512] f16)
__global__ void sum_h(const f16* __restrict__ a, const f16* __restrict__ b,
                      f16* __restrict__ r) {
  size_t i = ((size_t)blockIdx.x * 256 + threadIdx.x) * 8;
  f16x8 va = *(const f16x8*)(a + i), vb = *(const f16x8*)(b + i);
  *(f16x8*)(r + i) = va + vb;
}

// ---------------------------------------------------------------- recurrence
// Role WG: 512 thr, 8 waves: mtile=wave&1 (16 batch rows), gate=wave>>1.
// Owns 16 h-cols (j0=wgi*16) => 64 gate cols. Wk,Wr frags resident in VGPRs.
// FAST=1: ring [2][1024][32][512] f16, plain L2 stores/loads (same XCD).
// FAST=0: ring [2][8][32][512] f16, agent stores / agent loads (MALL).
template <int FAST>
__global__ __launch_bounds__(512, 1) void lstm_rec3(
    const f16* __restrict__ xh,     // [1024][32][512] layer input, time-major
    const float* __restrict__ WkAll,// [2][2][512][2048] f32
    const float* __restrict__ WrAll,// [2][2][512][2048] f32
    const float* __restrict__ biasAll, // [2][2][2048]
    const void* __restrict__ maskp,
    f16* __restrict__ ringb,
    unsigned* __restrict__ flags,   // [2][1024][32] u32, pre-zeroed (MALL)
    Claim* __restrict__ cl,         // pre-zeroed
    float* __restrict__ out,        // layer1: final output [b][t][512]
    const f16* __restrict__ res1h,  // layer1: residual, time-major
    const int layer) {
  const int tid = threadIdx.x, wave = tid >> 6, lane = tid & 63;

  // ---- role claim (tid 0), broadcast via LDS
  __shared__ int s_dir, s_wgi;
  if (tid == 0) {
    unsigned xcd;
    asm volatile("s_getreg_b32 %0, hwreg(HW_REG_XCC_ID)" : "=s"(xcd));
    xcd &= 7u;
    unsigned slot = AADD_U(&cl->cnt[xcd], 1u);
    int dir = -1, wgi = -1;
    if (slot < 32u) {
      if (slot == 31u) {  // XCD full: claim a direction
        unsigned d = AADD_U(&cl->dirclaim, 1u);
        int val = (d < 2u) ? (int)(d + 1u) : -1;
        __hip_atomic_store(&cl->xcddir[xcd], val, __ATOMIC_RELAXED, __HIP_MEMORY_SCOPE_AGENT);
      }
      while (true) {
        int v = __hip_atomic_load(&cl->xcddir[xcd], __ATOMIC_RELAXED, __HIP_MEMORY_SCOPE_AGENT);
        if (v != 0) { if (v > 0) { dir = v - 1; wgi = (int)slot; } break; }
        // escape: both dirs taken elsewhere and this XCD not full -> never chosen
        if (AL_U(&cl->dirclaim) >= 2u && AL_U(&cl->cnt[xcd]) < 32u) break;
        __builtin_amdgcn_s_sleep(2);
      }
    }
    s_dir = dir; s_wgi = wgi;
  }
  __syncthreads();
  const int dir = s_dir, wgi = s_wgi;
  if (dir < 0) return;  // non-role WG

  const int mtile = wave & 1, gate = wave >> 1;
  const int j0 = wgi * 16;
  const int arow = mtile * 16 + (lane & 15);      // batch row (MFMA A lane)
  const int koff = (lane >> 4) << 3;              // k-offset within 32-chunk
  const int gcol = gate * H_ + j0 + (lane & 15);  // gate column (MFMA B lane)

  __shared__ float zbuf[32][65];

  // ---- resident weight fragments straight from f32 inputs (one-time)
  const float* WrL = WrAll + (size_t)(layer * 2 + dir) * H_ * G_;
  const float* WkL = WkAll + (size_t)(layer * 2 + dir) * H_ * G_;
  f16x8 wfr[16], wfk[16];
#pragma unroll
  for (int kt = 0; kt < 16; ++kt) {
    int kb = kt * 32 + koff;
#pragma unroll
    for (int e = 0; e < 8; ++e) {
      wfr[kt][e] = (f16)WrL[(size_t)(kb + e) * G_ + gcol];
      wfk[kt][e] = (f16)WkL[(size_t)(kb + e) * G_ + gcol];
    }
  }

  // gate-phase identity: thread = (batch cb, col cj)
  const int cb = tid >> 4, cj = tid & 15;
  const float* bb = biasAll + (size_t)(layer * 2 + dir) * G_;
  float bias4[4];
#pragma unroll
  for (int g = 0; g < 4; ++g) bias4[g] = bb[g * H_ + j0 + cj];

  const unsigned char* mbytes = (const unsigned char*)maskp;
  const unsigned* mwords = (const unsigned*)maskp;
  const bool bytelay = (mbytes[1] != 0);  // bool(1B) vs int32(4B) layout probe

  float hstate = 0.f, cstate = 0.f;
  const size_t BH = (size_t)B_ * H_;
  const unsigned* flagd = flags + (size_t)dir * T_ * 32;
  const f32x4 vzero = {0.f, 0.f, 0.f, 0.f};

  for (int s = 0; s < T_; ++s) {
    const int t = dir ? (T_ - 1 - s) : s;
    // ---- x-part: acc = x[t] @ Wk tile (no cross-WG dependency)
    const f16* xp = xh + ((size_t)t * B_ + arow) * H_ + koff;
    f32x4 acc0 = vzero, acc1 = vzero;
#pragma unroll
    for (int kt = 0; kt < 16; ++kt) {
      f16x8 xf = *(const f16x8*)(xp + kt * 32);
      if (kt & 1) acc1 = __builtin_amdgcn_mfma_f32_16x16x32_f16(xf, wfk[kt], acc1, 0, 0, 0);
      else        acc0 = __builtin_amdgcn_mfma_f32_16x16x32_f16(xf, wfk[kt], acc0, 0, 0, 0);
    }
    // gate-phase prefetches
    const size_t btm = (size_t)cb * T_ + t;
    const bool mv = bytelay ? (mbytes[btm] != 0) : (mwords[btm] != 0);
    float xr = 0.f;
    if (layer == 1 && dir == 0)
      xr = (float)res1h[((size_t)t * B_ + cb) * H_ + j0 + cj];

    // ---- wait for h[s-1]: wave 0 polls the 32-flag line, barrier releases
    if (s > 0) {
      if (wave == 0) {
        const unsigned* fl = flagd + (size_t)(s - 1) * 32;
        while (true) {
          unsigned v = (lane < 32) ? AL_U(fl + lane) : 1u;
          if (__ballot(v == 1u) == ~0ull) break;
        }
      }
      __syncthreads();
      // ---- h-part: read h[s-1], acc += h @ Wr tile
      if (FAST) {
        const int tprev = dir ? (T_ - s) : (s - 1);  // t index of step s-1
        const f16* hp = ringb + ((size_t)dir * T_ + tprev) * BH +
                        (size_t)arow * H_ + koff;
        f16x8 hfr[16];
#pragma unroll
        for (int kt = 0; kt < 16; ++kt) hfr[kt] = *(const f16x8*)(hp + kt * 32);
#pragma unroll
        for (int kt = 0; kt < 16; ++kt) {
          if (kt & 1) acc1 = __builtin_amdgcn_mfma_f32_16x16x32_f16(hfr[kt], wfr[kt], acc1, 0, 0, 0);
          else        acc0 = __builtin_amdgcn_mfma_f32_16x16x32_f16(hfr[kt], wfr[kt], acc0, 0, 0, 0);
        }
      } else {
        const f16* hp = ringb + ((size_t)dir * 8 + ((s - 1) & 7)) * BH +
                        (size_t)arow * H_ + koff;
#pragma unroll
        for (int kt = 0; kt < 16; ++kt) {
          unsigned long long a0 = AL_U((const unsigned long long*)(hp + kt * 32));
          unsigned long long a1 = AL_U((const unsigned long long*)(hp + kt * 32 + 4));
          union { unsigned long long u[2]; f16x8 v; } cvt;
          cvt.u[0] = a0; cvt.u[1] = a1;
          if (kt & 1) acc1 = __builtin_amdgcn_mfma_f32_16x16x32_f16(cvt.v, wfr[kt], acc1, 0, 0, 0);
          else        acc0 = __builtin_amdgcn_mfma_f32_16x16x32_f16(cvt.v, wfr[kt], acc0, 0, 0, 0);
        }
      }
    }
    // ---- spill z tile: row=(lane>>4)*4+r (batch), col=lane&15
    {
      int zr = mtile * 16 + ((lane >> 4) << 2), zc = gate * 16 + (lane & 15);
#pragma unroll
      for (int r = 0; r < 4; ++r) zbuf[zr + r][zc] = acc0[r] + acc1[r];
    }
    __syncthreads();

    // ---- gates (fp32 state)
    float zi = zbuf[cb][cj]      + bias4[0];
    float zf = zbuf[cb][16 + cj] + bias4[1];
    float zg = zbuf[cb][32 + cj] + bias4[2];
    float zo = zbuf[cb][48 + cj] + bias4[3];
    float ig = sigm(zi), fg = sigm(zf), gg = tanh_(zg), og = sigm(zo);
    float cn = fg * cstate + ig * gg;
    float hn = og * tanh_(cn);
    if (mv) { cstate = cn; hstate = hn; }  // masked steps carry h,c

    // ---- publish h (packed 2xf16 per u32)
    f16 h16 = (f16)hstate;
    unsigned short hu = __builtin_bit_cast(unsigned short, h16);
    unsigned ob = (unsigned)__shfl_xor((int)hu, 1);
    unsigned pk = (unsigned)hu | ((ob & 0xffffu) << 16);
    if ((cj & 1) == 0) {
      if (FAST) {  // plain store -> XCD-local L2 (also the layer-0 output)
        *(unsigned*)(ringb + ((size_t)dir * T_ + t) * BH + (size_t)cb * H_ + j0 + cj) = pk;
      } else {
        AS_U((unsigned*)(ringb + ((size_t)dir * 8 + (s & 7)) * BH + (size_t)cb * H_ + j0 + cj), pk);
      }
    }
    // ---- release: drain stores, all waves done, then signal step s
    asm volatile("s_waitcnt vmcnt(0)" ::: "memory");
    __syncthreads();
    if (tid == 0) AS_U((unsigned*)(flagd + (size_t)s * 32 + wgi), 1u);

    // ---- layer-1 output (off critical path, after flag)
    if (layer == 1) {
      atomicAdd(&out[btm * H_ + j0 + cj], hstate + xr);
    }
  }
}

// ---------------------------------------------------------------- launch
extern "C" void kernel_launch(void* const* d_in, const int* in_sizes, int n_in,
                              void* d_out, int out_size, void* d_ws, size_t ws_size,
                              hipStream_t stream) {
  const float* x = (const float*)d_in[0];
  const void* maskp = (const void*)d_in[1];
  const float* Wk = (const float*)d_in[2];
  const float* Wr = (const float*)d_in[3];
  const float* bias = (const float*)d_in[4];
  float* out = (float*)d_out;
  (void)in_sizes; (void)n_in;

  // ---- workspace carve
  char* ws = (char*)d_ws;
  f16* xh = (f16*)(ws);                              // 33,554,432 (reused as res1h)
  unsigned* flags0 = (unsigned*)(ws + 33554432ull);  //    262,144 [2][1024][32] u32
  unsigned* flags1 = (unsigned*)(ws + 33816576ull);  //    262,144
  Claim* cl0 = (Claim*)(ws + 34078720ull);           //      1,024
  Claim* cl1 = (Claim*)(ws + 34079744ull);           //      1,024
  f16* ringS = (f16*)(ws + 34080768ull);             //    524,288 [2][8][32][512]
  f16* ring1 = (f16*)(ws + 34605056ull);             // 67,108,864 [2][1024][32][512] (fast only)
  const size_t MIN_NEED = 34605056ull;
  const size_t FAST_NEED = 34605056ull + 67108864ull;
  if (ws_size < MIN_NEED) return;  // fail loudly (wrong output), don't fault
  const bool fast1 = (ws_size >= FAST_NEED);

  // layer-0 ring = d_out scratch (f16 [2][1024][32][512] = 64 MiB exactly)
  f16* ring0 = (f16*)d_out;
  f16* hf = ring0;
  f16* hb = ring0 + (size_t)T_ * B_ * H_;

  hipMemsetAsync(flags0, 0, 526336ull, stream);  // flags0+flags1+cl0+cl1
  cvt_x_t<<<8192, 256, 0, stream>>>(x, xh);

  // layer 0: h ring lives in d_out (doubles as fwd/bwd h output scratch)
  lstm_rec3<1><<<512, 512, 0, stream>>>(xh, Wk, Wr, bias, maskp, ring0, flags0,
                                        cl0, (float*)nullptr, (const f16*)nullptr, 0);
  sum_h<<<8192, 256, 0, stream>>>(hf, hb, xh);  // res1h overwrites xh

  // layer 1: final output = fwd2 + bwd2 + res1
  hipMemsetAsync(d_out, 0, 67108864ull, stream);
  if (fast1) {
    lstm_rec3<1><<<512, 512, 0, stream>>>(xh, Wk, Wr, bias, maskp, ring1, flags1,
                                          cl1, out, xh, 1);
  } else {
    lstm_rec3<0><<<512, 512, 0, stream>>>(xh, Wk, Wr, bias, maskp, ringS, flags1,
                                          cl1, out, xh, 1);
  }
}

// Round 4
// 6091.264 us; speedup vs baseline: 4.2044x; 3.0161x over previous
//
#include <hip/hip_runtime.h>
#include <stdint.h>

// Encoder: 2-layer bidirectional masked LSTM. B=32 T=1024 D=H=512 G=4H=2048.
// v4: fix the v3 bottleneck (weight spill + scattered frag loads).
//  - wave = (mtile, kq): 16 batch rows x 128-K chunk, all 4 gates.
//    Wr frags: 64 VGPR resident. Wk: 64KB LDS, conflict-free lane*16B reads.
//  - xh / h-ring layouts are fragment-native [t][kb16][b][c16] f16 so all
//    global frag loads and the h publish are fully coalesced.
//  - partial-K accs summed via zbuf[4][32][64] LDS.
//  - comm identical to v3: XCD claim, MALL flags, wave0 agent poll.

#define B_ 32
#define T_ 1024
#define H_ 512
#define G_ 2048

typedef _Float16 f16;
typedef _Float16 f16x8 __attribute__((ext_vector_type(8)));
typedef float f32x4 __attribute__((ext_vector_type(4)));

#define AL_U(p) __hip_atomic_load((p), __ATOMIC_RELAXED, __HIP_MEMORY_SCOPE_AGENT)
#define AS_U(p, v) __hip_atomic_store((p), (v), __ATOMIC_RELAXED, __HIP_MEMORY_SCOPE_AGENT)
#define AADD_U(p, v) __hip_atomic_fetch_add((p), (v), __ATOMIC_RELAXED, __HIP_MEMORY_SCOPE_AGENT)

struct Claim {
  unsigned cnt[8];
  unsigned dirclaim;
  int xcddir[8];   // 0=undecided, 1/2=dir+1, -1=unused XCD
  unsigned pad[15];
};

__device__ __forceinline__ float sigm(float x) { return 1.f / (1.f + __expf(-x)); }
__device__ __forceinline__ float tanh_(float x) { return 1.f - 2.f / (__expf(2.f * x) + 1.f); }

// ---------------------------------------------------------------- converts
// x [b][t][512] f32 -> xh [t][kb32][b][c16] f16  (fragment-native)
__global__ void cvt_x_t(const float* __restrict__ x, f16* __restrict__ xh) {
  size_t j = (size_t)blockIdx.x * 256 + threadIdx.x;  // 2,097,152 groups of 8
  int t = (int)(j >> 11);
  int g = (int)(j & 2047);
  int b = g >> 6;
  int d0 = (g & 63) * 8;
  const float4* p = (const float4*)(x + ((size_t)b * T_ + t) * H_ + d0);
  float4 a = p[0], c = p[1];
  union { f16 h[8]; uint4 u; } r;
  r.h[0] = (f16)a.x; r.h[1] = (f16)a.y; r.h[2] = (f16)a.z; r.h[3] = (f16)a.w;
  r.h[4] = (f16)c.x; r.h[5] = (f16)c.y; r.h[6] = (f16)c.z; r.h[7] = (f16)c.w;
  size_t o = (((size_t)t * 32 + (d0 >> 4)) * 32 + b) * 16 + (d0 & 15);
  *(uint4*)(xh + o) = r.u;
}

// W [z4][512][2048] f32 -> Wb [z4][wg32][kt16][gate4][l64][e8] f16
// (per (z,wgi): a 64KB chunk in exact LDS/VGPR fragment order)
__global__ void cvt_w(const float* __restrict__ W, f16* __restrict__ Wb) {
  __shared__ float tl[32][65];
  const int wgi = blockIdx.x, kt = blockIdx.y, z = blockIdx.z;
  const float* src = W + (size_t)z * H_ * G_;
  const int k0 = kt * 32;
  for (int idx = threadIdx.x; idx < 2048; idx += 256) {
    int kk = idx >> 6, jj = idx & 63;
    int gate = jj >> 4, c = jj & 15;
    tl[kk][jj] = src[(size_t)(k0 + kk) * G_ + gate * H_ + wgi * 16 + c];
  }
  __syncthreads();
  const int gate = threadIdx.x >> 6, l = threadIdx.x & 63;
  const int c = l & 15, koff = (l >> 4) * 8;
  union { f16 h[8]; uint4 u; } v;
#pragma unroll
  for (int e = 0; e < 8; ++e) v.h[e] = (f16)tl[koff + e][gate * 16 + c];
  f16* dst = Wb + ((size_t)z * 32 + wgi) * 32768 + ((size_t)(kt * 4 + gate) * 64 + l) * 8;
  *(uint4*)dst = v.u;
}

// res1h = hf + hb (elementwise, layout-agnostic)
__global__ void sum_h(const f16* __restrict__ a, const f16* __restrict__ b,
                      f16* __restrict__ r) {
  size_t i = ((size_t)blockIdx.x * 256 + threadIdx.x) * 8;
  f16x8 va = *(const f16x8*)(a + i), vb = *(const f16x8*)(b + i);
  *(f16x8*)(r + i) = va + vb;
}

// ---------------------------------------------------------------- recurrence
// 512 WGs launched; claim -> 32 role WGs per direction on one XCD each.
// Role WG: 512 thr, wave=(mtile=wave&1, kq=wave>>1). Owns h-cols [wgi*16,+16).
// LAYER0: ring = d_out scratch, full history [dir][t][kb][b][c] (= hf/hb out).
// LAYER1: ring = 8-slot [dir][slot8][kb][b][c]; out += h (+res for dir0).
template <int LAYER>
__global__ __launch_bounds__(512, 2) void lstm_rec4(
    const f16* __restrict__ xh,     // [t][kb32][b][c16]
    const f16* __restrict__ wkb,    // [z4][wg32][64KB chunks]
    const f16* __restrict__ wrb,
    const float* __restrict__ biasAll,  // [2][2][2048]
    const void* __restrict__ maskp,
    f16* __restrict__ ring,
    unsigned* __restrict__ flags,   // [2][1024][32] u32, pre-zeroed (MALL)
    Claim* __restrict__ cl,         // pre-zeroed
    float* __restrict__ out,        // LAYER1 only
    const f16* __restrict__ res1h)  // LAYER1 only, [t][kb][b][c]
{
  const int tid = threadIdx.x, wave = tid >> 6, lane = tid & 63;

  // ---- role claim (tid 0), broadcast via LDS (same as v3)
  __shared__ int s_dir, s_wgi;
  if (tid == 0) {
    unsigned xcd;
    asm volatile("s_getreg_b32 %0, hwreg(HW_REG_XCC_ID)" : "=s"(xcd));
    xcd &= 7u;
    unsigned slot = AADD_U(&cl->cnt[xcd], 1u);
    int dir = -1, wgi = -1;
    if (slot < 32u) {
      if (slot == 31u) {
        unsigned d = AADD_U(&cl->dirclaim, 1u);
        int val = (d < 2u) ? (int)(d + 1u) : -1;
        __hip_atomic_store(&cl->xcddir[xcd], val, __ATOMIC_RELAXED, __HIP_MEMORY_SCOPE_AGENT);
      }
      while (true) {
        int v = __hip_atomic_load(&cl->xcddir[xcd], __ATOMIC_RELAXED, __HIP_MEMORY_SCOPE_AGENT);
        if (v != 0) { if (v > 0) { dir = v - 1; wgi = (int)slot; } break; }
        if (AL_U(&cl->dirclaim) >= 2u && AL_U(&cl->cnt[xcd]) < 32u) break;
        __builtin_amdgcn_s_sleep(2);
      }
    }
    s_dir = dir; s_wgi = wgi;
  }
  __syncthreads();
  const int dir = s_dir, wgi = s_wgi;
  if (dir < 0) return;

  const int mtile = wave & 1, kq = wave >> 1;  // kq in 0..3, kt = kq*4..+4
  const int j0 = wgi * 16;
  const int z = LAYER * 2 + dir;

  __shared__ f16 wkl[32768];          // 64KB Wk chunk, fragment-linear
  __shared__ float zbuf[4][32][64];   // 32KB partial-K z

  // ---- Wk chunk -> LDS (coalesced 64KB copy)
  {
    const f16* wkc = wkb + ((size_t)z * 32 + wgi) * 32768;
#pragma unroll
    for (int r = 0; r < 8; ++r)
      *(uint4*)&wkl[(size_t)(r * 512 + tid) * 8] = *(const uint4*)(wkc + (size_t)(r * 512 + tid) * 8);
  }
  // ---- Wr frags -> VGPR (64 regs)
  f16x8 wfr[4][4];
  {
    const f16* wrc = wrb + ((size_t)z * 32 + wgi) * 32768;
#pragma unroll
    for (int i = 0; i < 4; ++i) {
      int ktg = kq * 4 + i;
#pragma unroll
      for (int g = 0; g < 4; ++g)
        wfr[i][g] = *(const f16x8*)(wrc + ((size_t)(ktg * 4 + g) * 64 + lane) * 8);
    }
  }
  __syncthreads();  // wkl ready

  // frag addressing for this lane
  const int arow = mtile * 16 + (lane & 15);
  const int lkb = lane >> 5;                 // kb offset within kt (0/1)
  const int c0 = ((lane >> 4) & 1) * 8;      // col offset within kb

  // gate-phase identity
  const int cb = tid >> 4, cj = tid & 15;
  const float* bb = biasAll + (size_t)z * G_;
  float bias4[4];
#pragma unroll
  for (int g = 0; g < 4; ++g) bias4[g] = bb[g * H_ + j0 + cj];

  const unsigned char* mbytes = (const unsigned char*)maskp;
  const unsigned* mwords = (const unsigned*)maskp;
  const bool bytelay = (mbytes[1] != 0);

  float hstate = 0.f, cstate = 0.f;
  const unsigned* flagd = flags + (size_t)dir * T_ * 32;
  const f32x4 vzero = {0.f, 0.f, 0.f, 0.f};

  for (int s = 0; s < T_; ++s) {
    const int t = dir ? (T_ - 1 - s) : s;
    // ---- x-part: acc[g] = x[t] @ Wk (kq chunk) — overlaps the wait
    const f16* xb = xh + (size_t)t * 16384;
    f32x4 acc[4] = {vzero, vzero, vzero, vzero};
#pragma unroll
    for (int i = 0; i < 4; ++i) {
      const int ktg = kq * 4 + i;
      f16x8 xf = *(const f16x8*)(xb + ((size_t)(ktg * 2 + lkb) * 32 + arow) * 16 + c0);
#pragma unroll
      for (int g = 0; g < 4; ++g) {
        f16x8 wk = *(const f16x8*)&wkl[((size_t)(ktg * 4 + g) * 64 + lane) * 8];
        acc[g] = __builtin_amdgcn_mfma_f32_16x16x32_f16(xf, wk, acc[g], 0, 0, 0);
      }
    }
    // gate-phase prefetches
    const size_t btm = (size_t)cb * T_ + t;
    const bool mv = bytelay ? (mbytes[btm] != 0) : (mwords[btm] != 0);
    float xr = 0.f;
    if (LAYER == 1 && dir == 0)
      xr = (float)res1h[(((size_t)t * 32 + wgi) * 32 + cb) * 16 + cj];

    // ---- wait for h[s-1] (wave0 polls MALL flags), then h-part
    if (s > 0) {
      if (wave == 0) {
        const unsigned* fl = flagd + (size_t)(s - 1) * 32 + (lane & 31);
        while (true) {
          unsigned v = AL_U(fl);
          if (__ballot(v == 1u) == ~0ull) break;
        }
      }
      __syncthreads();
      const f16* hbase;
      if (LAYER == 0) {
        const int tprev = dir ? (T_ - s) : (s - 1);
        hbase = ring + ((size_t)dir * T_ + tprev) * 16384;
      } else {
        hbase = ring + ((size_t)dir * 8 + ((s - 1) & 7)) * 16384;
      }
#pragma unroll
      for (int i = 0; i < 4; ++i) {
        const int ktg = kq * 4 + i;
        f16x8 hf = *(const f16x8*)(hbase + ((size_t)(ktg * 2 + lkb) * 32 + arow) * 16 + c0);
#pragma unroll
        for (int g = 0; g < 4; ++g)
          acc[g] = __builtin_amdgcn_mfma_f32_16x16x32_f16(hf, wfr[i][g], acc[g], 0, 0, 0);
      }
    }
    // ---- spill partial z: D row=(lane>>4)*4+r, col=lane&15
    {
      const int zr = mtile * 16 + ((lane >> 4) << 2);
      const int zc = lane & 15;
#pragma unroll
      for (int g = 0; g < 4; ++g)
#pragma unroll
        for (int r = 0; r < 4; ++r) zbuf[kq][zr + r][g * 16 + zc] = acc[g][r];
    }
    __syncthreads();

    // ---- gates (fp32 state): sum 4 K-partials
    float z4[4];
#pragma unroll
    for (int g = 0; g < 4; ++g)
      z4[g] = zbuf[0][cb][g * 16 + cj] + zbuf[1][cb][g * 16 + cj] +
              zbuf[2][cb][g * 16 + cj] + zbuf[3][cb][g * 16 + cj] + bias4[g];
    float ig = sigm(z4[0]), fg = sigm(z4[1]), gg = tanh_(z4[2]), og = sigm(z4[3]);
    float cn = fg * cstate + ig * gg;
    float hn = og * tanh_(cn);
    if (mv) { cstate = cn; hstate = hn; }

    // ---- publish h: [.. ][kb=wgi][b][c] -> 1KB contiguous per WG
    f16 h16 = (f16)hstate;
    unsigned short hu = __builtin_bit_cast(unsigned short, h16);
    unsigned ob = (unsigned)__shfl_xor((int)hu, 1);
    unsigned pk = (unsigned)hu | ((ob & 0xffffu) << 16);
    if ((cj & 1) == 0) {
      f16* pb;
      if (LAYER == 0) pb = ring + ((size_t)dir * T_ + t) * 16384;
      else            pb = ring + ((size_t)dir * 8 + (s & 7)) * 16384;
      *(unsigned*)(pb + (size_t)wgi * 512 + tid) = pk;  // byte = (wgi*512+tid)*2
    }
    // ---- release: drain publish, all waves done, signal step s
    asm volatile("s_waitcnt vmcnt(0)" ::: "memory");
    __syncthreads();
    if (tid == 0) AS_U((unsigned*)(flagd + (size_t)s * 32 + wgi), 1u);

    // ---- layer-1 output (off critical path)
    if (LAYER == 1) {
      atomicAdd(&out[btm * H_ + j0 + cj], hstate + xr);
    }
  }
}

// ---------------------------------------------------------------- launch
extern "C" void kernel_launch(void* const* d_in, const int* in_sizes, int n_in,
                              void* d_out, int out_size, void* d_ws, size_t ws_size,
                              hipStream_t stream) {
  const float* x = (const float*)d_in[0];
  const void* maskp = (const void*)d_in[1];
  const float* Wk = (const float*)d_in[2];
  const float* Wr = (const float*)d_in[3];
  const float* bias = (const float*)d_in[4];
  float* out = (float*)d_out;
  (void)in_sizes; (void)n_in;

  // ---- workspace carve (51,382,272 B = 49 MiB)
  char* ws = (char*)d_ws;
  f16* xh = (f16*)(ws);                              // 33,554,432 (reused as res1h)
  f16* wkb = (f16*)(ws + 33554432ull);               //  8,388,608 [4][32][32768]
  f16* wrb = (f16*)(ws + 41943040ull);               //  8,388,608
  unsigned* flags0 = (unsigned*)(ws + 50331648ull);  //    262,144 [2][1024][32]
  unsigned* flags1 = (unsigned*)(ws + 50593792ull);  //    262,144
  Claim* cl0 = (Claim*)(ws + 50855936ull);           //      1,024
  Claim* cl1 = (Claim*)(ws + 50856960ull);           //      1,024
  f16* ring1 = (f16*)(ws + 50857984ull);             //    524,288 [2][8][32][32][16]
  if (ws_size < 51382272ull) return;  // fail loudly (wrong output), don't fault

  // layer-0 ring = d_out scratch: [dir][t][kb][b][c] f16 = 64 MiB (hf|hb)
  f16* ring0 = (f16*)d_out;
  f16* hf = ring0;
  f16* hb = ring0 + (size_t)T_ * 16384;

  hipMemsetAsync(flags0, 0, 526336ull, stream);  // flags0+flags1+cl0+cl1
  cvt_x_t<<<8192, 256, 0, stream>>>(x, xh);
  cvt_w<<<dim3(32, 16, 4), 256, 0, stream>>>(Wk, wkb);
  cvt_w<<<dim3(32, 16, 4), 256, 0, stream>>>(Wr, wrb);

  // layer 0
  lstm_rec4<0><<<512, 512, 0, stream>>>(xh, wkb, wrb, bias, maskp, ring0, flags0,
                                        cl0, (float*)nullptr, (const f16*)nullptr);
  sum_h<<<8192, 256, 0, stream>>>(hf, hb, xh);  // res1h overwrites xh

  // layer 1
  hipMemsetAsync(d_out, 0, 67108864ull, stream);
  lstm_rec4<1><<<512, 512, 0, stream>>>(xh, wkb, wrb, bias, maskp, ring1, flags1,
                                        cl1, out, xh);
}